// Round 6
// baseline (1257.617 us; speedup 1.0000x reference)
//
#include <hip/hip_runtime.h>
#include <hip/hip_bf16.h>
#include <stdint.h>

// ---------------------------------------------------------------------------
// out = net(x) + P(net(P(x))), P = swap (W,X)<->(Y,Z).  Equivariance:
// P(net(P(x);W)) = net(x; P_w(W)) -> one network, 2 weight branches.
//
// Round 6: conv2 on mfma_f32_32x32x16 with z-shift-pair N packing.
//   N = 32 = (16co x 2 z-shifts), K = 16ci x 1 A-tap (dy, dzA in 0..3),
//   B = Toeplitz-banded weights pre-packed per lane (75% slot efficiency),
//   read from global/L2 directly into regs (off the LDS pipe).
//   M = 32 even-z positions; A slab = full padded plane in LDS, parity-split
//   48-B cells -> conflict-free ds_read_b128.  2x fewer LDS reads per MAC.
// Also: prep_weights parallelized (was 63us on 1 block); conv1 does both
// branches per block (shared x staging).  conv3 unchanged from round 5.
// ---------------------------------------------------------------------------

#define S   24
#define S2  576
#define S3  13824
#define S4  331776

typedef __attribute__((ext_vector_type(8)))  short bf16x8;
typedef __attribute__((ext_vector_type(4)))  float f32x4;
typedef __attribute__((ext_vector_type(16))) float f32x16;
typedef __attribute__((ext_vector_type(4)))  int   i32x4;

__device__ __forceinline__ uint32_t f2bf(float f) {            // RNE f32->bf16
    uint32_t u = __float_as_uint(f);
    return (u + 0x7FFFu + ((u >> 16) & 1u)) >> 16;
}
__device__ __forceinline__ int permtap(int t) {                // (kw,kx,ky,kz)->(ky,kz,kw,kx)
    int kw = t / 27, kx = (t / 9) % 3, ky = (t / 3) % 3, kz = t % 3;
    return ky * 27 + kz * 9 + kw * 3 + kx;
}

// ---------------- workspace map (bytes) ----------------
// Wp1  f32  [2br][81][16co]            @ 0        10368
// Wp3c bf16 [2br][81][16ci]            @ 10368    5184    (ends 15552)
// Wp2T bf16 [2br][9ph][12a][64l][8j]   @ 16384    221184  (ends 237568)
// y1p  bf16 [2br][576wx][676yz][16]    @ 262144   24920064 (ends 25182208)
// y2p  bf16 [576wx][676yz][2br*16]     @ 25182208 24920064 (ends 50102272)
#define WP1_OFF   0
#define WP3C_OFF  10368
#define WP2T_OFF  16384
#define Y1P_OFF   262144
#define Y1P_PER_BR 12460032
#define Y2P_OFF   25182208
#define WS_NEED   50102272ull

// ---------------- prep: pack weights (parallel) ----------------
__global__ void prep_weights(const float* __restrict__ w1, const float* __restrict__ w2,
                             const float* __restrict__ w3,
                             float* __restrict__ Wp1, ushort* __restrict__ Wp3c,
                             ushort* __restrict__ Wp2T) {
    const int bid = blockIdx.x, tid = threadIdx.x;
    if (bid < 432) {
        int i = bid * 256 + tid;                    // 110592 Wp2T elements
        int j = i & 7, lane = (i >> 3) & 63, rest = i >> 9;   // rest=(br*9+ph)*12+a
        int a = rest % 12, ph = (rest / 12) % 9, br = rest / 108;
        int col = lane & 31, co = col & 15, s = col >> 4;
        int ci = (lane >> 5) * 8 + j;
        int dy = a >> 2, dzA = a & 3, dz = dzA - s;
        ushort v = 0;
        if (dz >= 0 && dz <= 2) {
            int dw = ph / 3, dx = ph % 3;
            int t = dw * 27 + dx * 9 + dy * 3 + dz;
            int ts = br ? permtap(t) : t;
            v = (ushort)f2bf(w2[(co * 16 + ci) * 81 + ts]);
        }
        Wp2T[i] = v;
    } else {
        int i = (bid - 432) * 256 + tid;
        if (i < 2592) {
            int ci = i & 15, t = (i >> 4) % 81, br = i / 1296;
            int ts = br ? permtap(t) : t;
            Wp1[i]  = w1[ci * 81 + ts];
            Wp3c[i] = (ushort)f2bf(w3[ci * 81 + ts]);
        }
    }
}

// ---------------- zero fill (y1p + y2p halo init) ----------------
__global__ void zero_ws(uint4* __restrict__ p, int n4) {
    int i = blockIdx.x * blockDim.x + threadIdx.x;
    int stride = gridDim.x * blockDim.x;
    for (; i < n4; i += stride) p[i] = make_uint4(0u, 0u, 0u, 0u);
}

// ---------------- conv1: x (1ch f32) -> y1p (16ch bf16, padded), BOTH br ----
__global__ __launch_bounds__(576) void conv1_plane2(
    const float* __restrict__ xn, const float* __restrict__ Wp1g,
    const float* __restrict__ b1, uint32_t* __restrict__ y1p0) {
    __shared__ float xl[9 * 676];
    const int tid = threadIdx.x;
    const int w = blockIdx.x / 24, xx = blockIdx.x % 24;
    for (int g = tid; g < 6084; g += 576) {
        int wi = g / 2028, r1 = g - wi * 2028;
        int xi = r1 / 676, r2 = r1 - xi * 676;
        int yp = r2 / 26, zp = r2 - yp * 26;
        int ws_ = w + wi - 1, xs = xx + xi - 1, ys = yp - 1, zs = zp - 1;
        float v = 0.f;
        if ((unsigned)ws_ < 24u && (unsigned)xs < 24u && (unsigned)ys < 24u && (unsigned)zs < 24u)
            v = xn[((ws_ * 24 + xs) * 24 + ys) * 24 + zs];
        xl[g] = v;
    }
    __syncthreads();
    const int yy = tid / 24, zz = tid - yy * 24;
    float a0[16], a1[16];
#pragma unroll
    for (int c = 0; c < 16; ++c) { a0[c] = 0.f; a1[c] = 0.f; }
#pragma unroll 1
    for (int dw = 0; dw < 3; ++dw)
#pragma unroll 1
        for (int dx = 0; dx < 3; ++dx) {
            const float* xp = &xl[(dw * 3 + dx) * 676];
#pragma unroll
            for (int dy = 0; dy < 3; ++dy)
#pragma unroll
                for (int dz = 0; dz < 3; ++dz) {
                    float xv = xp[(yy + dy) * 26 + (zz + dz)];
                    const int t = ((dw * 3 + dx) * 3 + dy) * 3 + dz;
                    const float* wt0 = &Wp1g[t << 4];
                    const float* wt1 = &Wp1g[1296 + (t << 4)];
#pragma unroll
                    for (int c = 0; c < 16; ++c) {
                        a0[c] = fmaf(xv, wt0[c], a0[c]);
                        a1[c] = fmaf(xv, wt1[c], a1[c]);
                    }
                }
        }
    const size_t rec = (size_t)((w * 24 + xx) * 26 + yy + 1) * 26 + zz + 1;
    uint32_t pk[8];
#pragma unroll
    for (int cp = 0; cp < 8; ++cp) {
        float a = fmaxf(a0[2 * cp]     + b1[2 * cp],     0.f);
        float b = fmaxf(a0[2 * cp + 1] + b1[2 * cp + 1], 0.f);
        pk[cp] = f2bf(a) | (f2bf(b) << 16);
    }
    uint32_t* dst0 = y1p0 + rec * 8;
    *(uint4*)dst0       = make_uint4(pk[0], pk[1], pk[2], pk[3]);
    *(uint4*)(dst0 + 4) = make_uint4(pk[4], pk[5], pk[6], pk[7]);
#pragma unroll
    for (int cp = 0; cp < 8; ++cp) {
        float a = fmaxf(a1[2 * cp]     + b1[2 * cp],     0.f);
        float b = fmaxf(a1[2 * cp + 1] + b1[2 * cp + 1], 0.f);
        pk[cp] = f2bf(a) | (f2bf(b) << 16);
    }
    uint32_t* dst1 = y1p0 + (size_t)(Y1P_PER_BR / 4) + rec * 8;
    *(uint4*)dst1       = make_uint4(pk[0], pk[1], pk[2], pk[3]);
    *(uint4*)(dst1 + 4) = make_uint4(pk[4], pk[5], pk[6], pk[7]);
}

// ---------------- conv2: 32x32x16 MFMA, z-shift-pair N packing --------------
// grid 1152 = 2br x 576 (w,x) planes (XCD-swizzled); block 576 = 9 waves.
// Wave = one M-tile of 32 even-z positions (s in {0,1} -> 64 outputs x 16co).
// LDS A slab: parity-split [2][26y][13z'] cells of 48B (32B data), dbuf.
#define RING2 32448

__global__ __launch_bounds__(576) void conv2_mfma2(
    const char* __restrict__ y1p0, const char* __restrict__ Wp2T,
    const float* __restrict__ b2, ushort* __restrict__ y2p) {
    __shared__ char lds[2 * RING2];
    const int tid = threadIdx.x, lane = tid & 63, wid = tid >> 6;
    const int bid = blockIdx.x;
    const int wg = (bid & 7) * 144 + (bid >> 3);        // bijective (1152%8==0)
    const int br = wg / 576, pb = wg - br * 576;
    const int w = pb / 24, xx = pb % 24;
    const char* y1p = y1p0 + (size_t)br * Y1P_PER_BR;
    ushort* y2b = y2p + br * 16;

    const int row = lane & 31, half = lane >> 5;
    const int p = wid * 32 + row;
    const int y_r = p / 12, zer = (p - y_r * 12) * 2;
    int aoff[12];
#pragma unroll
    for (int a = 0; a < 12; ++a) {
        int dy = a >> 2, dzA = a & 3;
        int zp = zer + dzA, par = zp & 1, zq = zp >> 1;
        aoff[a] = par * 16224 + ((y_r + dy) * 13 + zq) * 48 + half * 16;
    }
    const char* Bbase = Wp2T + (size_t)br * 110592;     // 9ph*12a*1024

    f32x16 acc;
#pragma unroll
    for (int r = 0; r < 16; ++r) acc[r] = 0.f;

#define STAGE2(ph_, rb_) do {                                                       \
    int dw_ = (ph_) / 3, dx_ = (ph_) % 3;                                           \
    int wc_ = min(max(w + dw_ - 1, 0), 23), xc_ = min(max(xx + dx_ - 1, 0), 23);    \
    const char* plane_ = y1p + (size_t)((wc_ * 24 + xc_) * 676) * 32;               \
    _Pragma("unroll")                                                               \
    for (int it_ = 0; it_ < 4; ++it_) {                                             \
        int d_ = tid + it_ * 576;                                                   \
        if (d_ < 2028) {                                                            \
            int reg_ = d_ >= 1014;                                                  \
            int dd_ = d_ - reg_ * 1014;                                             \
            int cell_ = dd_ / 3, part_ = dd_ - cell_ * 3;                           \
            int yy_ = cell_ / 13, zq_ = cell_ - yy_ * 13;                           \
            int zp_ = zq_ * 2 + reg_;                                               \
            if (part_ < 2)                                                          \
                __builtin_amdgcn_global_load_lds(                                   \
                    (const __attribute__((address_space(1))) void*)                 \
                        (plane_ + (yy_ * 26 + zp_) * 32 + part_ * 16),              \
                    (__attribute__((address_space(3))) void*)                       \
                        (lds + (rb_) + ((tid & ~63) + it_ * 576) * 16),             \
                    16, 0, 0);                                                      \
        }                                                                           \
    }                                                                               \
} while (0)

    STAGE2(0, 0);
    int ring = 0;
#pragma unroll 1
    for (int ph = 0; ph < 9; ++ph) {
        __syncthreads();
        if (ph < 8) STAGE2(ph + 1, ring ^ RING2);
        int dw = ph / 3, dx = ph % 3;
        bool valid = ((unsigned)(w + dw - 1) < 24u) && ((unsigned)(xx + dx - 1) < 24u);
        if (valid) {
            const char* bp = Bbase + ph * 12288 + lane * 16;
            i32x4 bf[12];
#pragma unroll
            for (int a = 0; a < 12; ++a)
                bf[a] = *(const i32x4*)(bp + a * 1024);
#pragma unroll
            for (int a = 0; a < 12; ++a) {
                i32x4 avr = *(const i32x4*)(lds + ring + aoff[a]);
                acc = __builtin_amdgcn_mfma_f32_32x32x16_bf16(
                    __builtin_bit_cast(bf16x8, avr),
                    __builtin_bit_cast(bf16x8, bf[a]), acc, 0, 0, 0);
            }
        }
        ring ^= RING2;
    }
#undef STAGE2

    // epilogue: D col=lane&31 -> (co,s); row=(reg&3)+8*(reg>>2)+4*half
    const int co = lane & 15, s = (lane >> 4) & 1;
    const float bb = b2[co];
    const int plane676 = (w * 24 + xx) * 676;
#pragma unroll
    for (int r = 0; r < 16; ++r) {
        int rowD = (r & 3) + 8 * (r >> 2) + 4 * half;
        int pp = wid * 32 + rowD;
        int yo = pp / 12, ze = (pp - yo * 12) * 2;
        float v = fmaxf(acc[r] + bb, 0.f);
        y2b[(size_t)(plane676 + (yo + 1) * 26 + (ze + s + 1)) * 32 + co] = (ushort)f2bf(v);
    }
}

// ---------------- conv3: MFMA, branches in N cols 0/1 (round-5, proven) ----
#define RING3   20800
#define W3C_LDS 41600

__global__ __launch_bounds__(256) void conv3_mfma(
    const char* __restrict__ y2p, const char* __restrict__ Wp3c,
    const float* __restrict__ b3, float* __restrict__ outn) {
    __shared__ char lds[2 * RING3 + 5184];
    const int tid = threadIdx.x, lane = tid & 63, wid = tid >> 6;
    const int bid = blockIdx.x;
    const int wg = (bid & 7) * 216 + (bid >> 3);        // bijective (1728%8==0)
    const int w = wg / 72, r0 = wg % 72, xx = r0 / 3, y0 = (r0 % 3) * 8;

    const int col = lane & 15, g16 = (lane >> 4) & 3;
    const int pyA = (lane >> 3) & 1, pzA = lane & 7;
    int a3[9];
#pragma unroll
    for (int t = 0; t < 9; ++t) {
        int dy = t / 3, dz = t % 3;
        a3[t] = ((2 * wid + pyA + dy) * 26 + (pzA + dz)) * 80 + g16 * 16;
    }
    const bool bact = (col == 0 && g16 < 2) || (col == 1 && g16 >= 2);
    const int colsel = (col < 2) ? col : 0;
    const int b_base = W3C_LDS + colsel * 2592 + (g16 & 1) * 16;
    const int bmask = bact ? -1 : 0;

#pragma unroll
    for (int it = 0; it < 2; ++it) {
        int g = tid + it * 256;
        if (g < 324)
            __builtin_amdgcn_global_load_lds(
                (const __attribute__((address_space(1))) void*)(Wp3c + g * 16),
                (__attribute__((address_space(3))) void*)
                    (lds + W3C_LDS + ((tid & ~63) + it * 256) * 16),
                16, 0, 0);
    }

    f32x4 acc[3];
#pragma unroll
    for (int m = 0; m < 3; ++m) acc[m] = f32x4{0.f, 0.f, 0.f, 0.f};

#define STAGE3(ph_, rb_) do {                                                       \
    int dw_ = (ph_) / 3, dx_ = (ph_) % 3;                                           \
    int wc_ = min(max(w + dw_ - 1, 0), 23), xc_ = min(max(xx + dx_ - 1, 0), 23);    \
    const char* slab_ = y2p + (size_t)((wc_ * 24 + xc_) * 676 + y0 * 26) * 64;      \
    _Pragma("unroll")                                                               \
    for (int it_ = 0; it_ < 6; ++it_) {                                             \
        int g_ = tid + it_ * 256;                                                   \
        if (g_ < 1300) {                                                            \
            int c_ = g_ / 5, p_ = g_ - c_ * 5;                                      \
            if (p_ < 4)                                                             \
                __builtin_amdgcn_global_load_lds(                                   \
                    (const __attribute__((address_space(1))) void*)                 \
                        (slab_ + c_ * 64 + p_ * 16),                                \
                    (__attribute__((address_space(3))) void*)                       \
                        (lds + (rb_) + ((tid & ~63) + it_ * 256) * 16),             \
                    16, 0, 0);                                                      \
        }                                                                           \
    }                                                                               \
} while (0)

    STAGE3(0, 0);
    int ring = 0;
#pragma unroll 1
    for (int ph = 0; ph < 9; ++ph) {
        __syncthreads();
        if (ph < 8) STAGE3(ph + 1, ring ^ RING3);
        int dw = ph / 3, dx = ph % 3;
        bool valid = ((unsigned)(w + dw - 1) < 24u) && ((unsigned)(xx + dx - 1) < 24u);
        if (valid) {
#pragma unroll
            for (int tl = 0; tl < 9; ++tl) {
                int tap = ph * 9 + tl;
                i32x4 braw = *(const i32x4*)(lds + b_base + tap * 32);
                i32x4 bm;
                bm[0] = braw[0] & bmask; bm[1] = braw[1] & bmask;
                bm[2] = braw[2] & bmask; bm[3] = braw[3] & bmask;
#pragma unroll
                for (int m = 0; m < 3; ++m) {
                    i32x4 avr = *(const i32x4*)(lds + ring + a3[tl] + m * 640);
                    acc[m] = __builtin_amdgcn_mfma_f32_16x16x32_bf16(
                        __builtin_bit_cast(bf16x8, avr),
                        __builtin_bit_cast(bf16x8, bm), acc[m], 0, 0, 0);
                }
            }
        }
        ring ^= RING3;
    }
#undef STAGE3

    const float bv = b3[0];
    const int py = (lane >> 5) & 1, c4 = ((lane >> 4) & 1) * 4;
    const int yo = y0 + 2 * wid + py;
    float* obase = outn + ((size_t)(w * 24 + xx) * 24 + yo) * 24;
#pragma unroll
    for (int m = 0; m < 3; ++m) {
        float o[4];
#pragma unroll
        for (int r = 0; r < 4; ++r) {
            float mine = acc[m][r];
            float oth = __shfl_xor(mine, 1);
            o[r] = fmaxf(mine + bv, 0.f) + fmaxf(oth + bv, 0.f);
        }
        if (col == 0)
            *(float4*)(obase + m * 8 + c4) = make_float4(o[0], o[1], o[2], o[3]);
    }
}

extern "C" void kernel_launch(void* const* d_in, const int* in_sizes, int n_in,
                              void* d_out, int out_size, void* d_ws, size_t ws_size,
                              hipStream_t stream) {
    const float* x  = (const float*)d_in[0];
    const float* w1 = (const float*)d_in[1];
    const float* b1 = (const float*)d_in[2];
    const float* w2 = (const float*)d_in[3];
    const float* b2 = (const float*)d_in[4];
    const float* w3 = (const float*)d_in[5];
    const float* b3 = (const float*)d_in[6];
    float* out = (float*)d_out;
    char* ws = (char*)d_ws;
    if (ws_size < WS_NEED) return;

    float*  Wp1  = (float*)(ws + WP1_OFF);
    ushort* Wp3c = (ushort*)(ws + WP3C_OFF);
    ushort* Wp2T = (ushort*)(ws + WP2T_OFF);
    uint32_t* y1p_u32 = (uint32_t*)(ws + Y1P_OFF);
    const char* y1p_b = (const char*)(ws + Y1P_OFF);
    ushort* y2p = (ushort*)(ws + Y2P_OFF);

    prep_weights<<<444, 256, 0, stream>>>(w1, w2, w3, Wp1, Wp3c, Wp2T);
    zero_ws<<<2048, 256, 0, stream>>>((uint4*)(ws + Y1P_OFF),
                                      (int)((WS_NEED - Y1P_OFF) / 16));

    for (int n = 0; n < 8; ++n) {
        conv1_plane2<<<576, 576, 0, stream>>>(
            x + (size_t)n * S4, Wp1, b1, y1p_u32);
        conv2_mfma2<<<1152, 576, 0, stream>>>(
            y1p_b, (const char*)(ws + WP2T_OFF), b2, y2p);
        conv3_mfma<<<1728, 256, 0, stream>>>(
            (const char*)y2p, (const char*)(ws + WP3C_OFF), b3,
            out + (size_t)n * S4);
    }
}

// Round 7
// 1203.142 us; speedup vs baseline: 1.0453x; 1.0453x over previous
//
#include <hip/hip_runtime.h>
#include <hip/hip_bf16.h>
#include <stdint.h>

// ---------------------------------------------------------------------------
// out = net(x) + P(net(P(x))), P = swap (W,X)<->(Y,Z).  Equivariance:
// P(net(P(x);W)) = net(x; P_w(W)) -> one network, 2 weight branches.
//
// Round 7: conv2 z-shift MFMA kept, but re-blocked for occupancy/latency:
//   block = 3 waves (192thr) = one y-group of 8 rows (96 pos = 3 M-tiles),
//   A-slab 10y x 26z parity-split 48B cells = 12.48KB/buf, ring 25KB ->
//   6 blocks/CU (was 2).  9-phase loop FULLY UNROLLED; B-fragments for
//   phase ph+1 prefetched into registers while staging overlaps -> no
//   exposed B latency.  conv1/conv3/prep unchanged (proven).
// ---------------------------------------------------------------------------

#define S   24
#define S2  576
#define S3  13824
#define S4  331776

typedef __attribute__((ext_vector_type(8)))  short bf16x8;
typedef __attribute__((ext_vector_type(4)))  float f32x4;
typedef __attribute__((ext_vector_type(16))) float f32x16;
typedef __attribute__((ext_vector_type(4)))  int   i32x4;

__device__ __forceinline__ uint32_t f2bf(float f) {            // RNE f32->bf16
    uint32_t u = __float_as_uint(f);
    return (u + 0x7FFFu + ((u >> 16) & 1u)) >> 16;
}
__device__ __forceinline__ int permtap(int t) {                // (kw,kx,ky,kz)->(ky,kz,kw,kx)
    int kw = t / 27, kx = (t / 9) % 3, ky = (t / 3) % 3, kz = t % 3;
    return ky * 27 + kz * 9 + kw * 3 + kx;
}

// ---------------- workspace map (bytes) ----------------
#define WP1_OFF   0
#define WP3C_OFF  10368
#define WP2T_OFF  16384
#define Y1P_OFF   262144
#define Y1P_PER_BR 12460032
#define Y2P_OFF   25182208
#define WS_NEED   50102272ull

// ---------------- prep: pack weights (parallel) ----------------
__global__ void prep_weights(const float* __restrict__ w1, const float* __restrict__ w2,
                             const float* __restrict__ w3,
                             float* __restrict__ Wp1, ushort* __restrict__ Wp3c,
                             ushort* __restrict__ Wp2T) {
    const int bid = blockIdx.x, tid = threadIdx.x;
    if (bid < 432) {
        int i = bid * 256 + tid;                    // 110592 Wp2T elements
        int j = i & 7, lane = (i >> 3) & 63, rest = i >> 9;   // rest=(br*9+ph)*12+a
        int a = rest % 12, ph = (rest / 12) % 9, br = rest / 108;
        int col = lane & 31, co = col & 15, s = col >> 4;
        int ci = (lane >> 5) * 8 + j;
        int dy = a >> 2, dzA = a & 3, dz = dzA - s;
        ushort v = 0;
        if (dz >= 0 && dz <= 2) {
            int dw = ph / 3, dx = ph % 3;
            int t = dw * 27 + dx * 9 + dy * 3 + dz;
            int ts = br ? permtap(t) : t;
            v = (ushort)f2bf(w2[(co * 16 + ci) * 81 + ts]);
        }
        Wp2T[i] = v;
    } else {
        int i = (bid - 432) * 256 + tid;
        if (i < 2592) {
            int ci = i & 15, t = (i >> 4) % 81, br = i / 1296;
            int ts = br ? permtap(t) : t;
            Wp1[i]  = w1[ci * 81 + ts];
            Wp3c[i] = (ushort)f2bf(w3[ci * 81 + ts]);
        }
    }
}

// ---------------- zero fill (y1p + y2p halo init) ----------------
__global__ void zero_ws(uint4* __restrict__ p, int n4) {
    int i = blockIdx.x * blockDim.x + threadIdx.x;
    int stride = gridDim.x * blockDim.x;
    for (; i < n4; i += stride) p[i] = make_uint4(0u, 0u, 0u, 0u);
}

// ---------------- conv1: x (1ch f32) -> y1p (16ch bf16, padded), BOTH br ----
__global__ __launch_bounds__(576) void conv1_plane2(
    const float* __restrict__ xn, const float* __restrict__ Wp1g,
    const float* __restrict__ b1, uint32_t* __restrict__ y1p0) {
    __shared__ float xl[9 * 676];
    const int tid = threadIdx.x;
    const int w = blockIdx.x / 24, xx = blockIdx.x % 24;
    for (int g = tid; g < 6084; g += 576) {
        int wi = g / 2028, r1 = g - wi * 2028;
        int xi = r1 / 676, r2 = r1 - xi * 676;
        int yp = r2 / 26, zp = r2 - yp * 26;
        int ws_ = w + wi - 1, xs = xx + xi - 1, ys = yp - 1, zs = zp - 1;
        float v = 0.f;
        if ((unsigned)ws_ < 24u && (unsigned)xs < 24u && (unsigned)ys < 24u && (unsigned)zs < 24u)
            v = xn[((ws_ * 24 + xs) * 24 + ys) * 24 + zs];
        xl[g] = v;
    }
    __syncthreads();
    const int yy = tid / 24, zz = tid - yy * 24;
    float a0[16], a1[16];
#pragma unroll
    for (int c = 0; c < 16; ++c) { a0[c] = 0.f; a1[c] = 0.f; }
#pragma unroll 1
    for (int dw = 0; dw < 3; ++dw)
#pragma unroll 1
        for (int dx = 0; dx < 3; ++dx) {
            const float* xp = &xl[(dw * 3 + dx) * 676];
#pragma unroll
            for (int dy = 0; dy < 3; ++dy)
#pragma unroll
                for (int dz = 0; dz < 3; ++dz) {
                    float xv = xp[(yy + dy) * 26 + (zz + dz)];
                    const int t = ((dw * 3 + dx) * 3 + dy) * 3 + dz;
                    const float* wt0 = &Wp1g[t << 4];
                    const float* wt1 = &Wp1g[1296 + (t << 4)];
#pragma unroll
                    for (int c = 0; c < 16; ++c) {
                        a0[c] = fmaf(xv, wt0[c], a0[c]);
                        a1[c] = fmaf(xv, wt1[c], a1[c]);
                    }
                }
        }
    const size_t rec = (size_t)((w * 24 + xx) * 26 + yy + 1) * 26 + zz + 1;
    uint32_t pk[8];
#pragma unroll
    for (int cp = 0; cp < 8; ++cp) {
        float a = fmaxf(a0[2 * cp]     + b1[2 * cp],     0.f);
        float b = fmaxf(a0[2 * cp + 1] + b1[2 * cp + 1], 0.f);
        pk[cp] = f2bf(a) | (f2bf(b) << 16);
    }
    uint32_t* dst0 = y1p0 + rec * 8;
    *(uint4*)dst0       = make_uint4(pk[0], pk[1], pk[2], pk[3]);
    *(uint4*)(dst0 + 4) = make_uint4(pk[4], pk[5], pk[6], pk[7]);
#pragma unroll
    for (int cp = 0; cp < 8; ++cp) {
        float a = fmaxf(a1[2 * cp]     + b1[2 * cp],     0.f);
        float b = fmaxf(a1[2 * cp + 1] + b1[2 * cp + 1], 0.f);
        pk[cp] = f2bf(a) | (f2bf(b) << 16);
    }
    uint32_t* dst1 = y1p0 + (size_t)(Y1P_PER_BR / 4) + rec * 8;
    *(uint4*)dst1       = make_uint4(pk[0], pk[1], pk[2], pk[3]);
    *(uint4*)(dst1 + 4) = make_uint4(pk[4], pk[5], pk[6], pk[7]);
}

// ---------------- conv2 v3: 32x32x16 MFMA, y-group blocks, B-pipelined ------
// grid 3456 = 2br x 576 planes x 3 y-groups; block 192 = 3 waves.
// A slab: [2 par][10 yl][13 zq] cells 48B (32B data) = 12480 B, double-buffered.
#define RING2C 12480

__global__ __launch_bounds__(192) void conv2_mfma3(
    const char* __restrict__ y1p0, const char* __restrict__ Wp2T,
    const float* __restrict__ b2, ushort* __restrict__ y2p) {
    __shared__ char lds[2 * RING2C];
    const int tid = threadIdx.x, lane = tid & 63, wid = tid >> 6;
    const int bid = blockIdx.x;
    const int wg = (bid & 7) * 432 + (bid >> 3);        // bijective (3456%8==0)
    const int br = wg / 1728, r1 = wg - br * 1728;
    const int pb = r1 / 3, yg = r1 % 3, y0 = yg * 8;
    const int w = pb / 24, xx = pb % 24;
    const char* y1p = y1p0 + (size_t)br * Y1P_PER_BR;
    ushort* y2b = y2p + br * 16;

    const int row = lane & 31, half = lane >> 5;
    const int p = wid * 32 + row;                       // 0..95 within y-group
    const int y_r = p / 12, zer = (p - y_r * 12) * 2;
    int aoff[12];
#pragma unroll
    for (int a = 0; a < 12; ++a) {
        int dy = a >> 2, dzA = a & 3;
        int zp = zer + dzA, par = zp & 1, zq = zp >> 1;
        aoff[a] = par * 6240 + ((y_r + dy) * 13 + zq) * 48 + half * 16;
    }
    const char* Bbase = Wp2T + (size_t)br * 110592 + lane * 16;

    f32x16 acc;
#pragma unroll
    for (int r = 0; r < 16; ++r) acc[r] = 0.f;

#define STAGE2(ph_, rb_) do {                                                     \
    int dw_ = (ph_) / 3, dx_ = (ph_) % 3;                                         \
    int wc_ = min(max(w + dw_ - 1, 0), 23), xc_ = min(max(xx + dx_ - 1, 0), 23);  \
    const char* plane_ = y1p + (size_t)((wc_ * 24 + xc_) * 676) * 32;             \
    _Pragma("unroll")                                                             \
    for (int it_ = 0; it_ < 5; ++it_) {                                           \
        int g_ = tid + it_ * 192;                                                 \
        if (g_ < 780) {                                                           \
            int cell_ = g_ / 3, part_ = g_ - cell_ * 3;                           \
            int par_ = cell_ / 130, rem_ = cell_ - par_ * 130;                    \
            int yl_ = rem_ / 13, zq_ = rem_ - yl_ * 13;                           \
            int zp_ = zq_ * 2 + par_;                                             \
            if (part_ < 2)                                                        \
                __builtin_amdgcn_global_load_lds(                                 \
                    (const __attribute__((address_space(1))) void*)               \
                        (plane_ + ((y0 + yl_) * 26 + zp_) * 32 + part_ * 16),     \
                    (__attribute__((address_space(3))) void*)                     \
                        (lds + (rb_) + ((tid & ~63) + it_ * 192) * 16),           \
                    16, 0, 0);                                                    \
        }                                                                         \
    }                                                                             \
} while (0)

    i32x4 bcur[12], bnxt[12];
#pragma unroll
    for (int a = 0; a < 12; ++a)
        bcur[a] = *(const i32x4*)(Bbase + a * 1024);
    STAGE2(0, 0);

#pragma unroll
    for (int ph = 0; ph < 9; ++ph) {
        const int rb = (ph & 1) * RING2C;
        __syncthreads();                                 // slab[rb] ready
        if (ph < 8) STAGE2(ph + 1, rb ^ RING2C);
        if (ph < 8) {
            const char* bp = Bbase + (ph + 1) * 12288;
#pragma unroll
            for (int a = 0; a < 12; ++a)
                bnxt[a] = *(const i32x4*)(bp + a * 1024);
        }
        const int dw = ph / 3, dx = ph % 3;
        const bool valid = ((unsigned)(w + dw - 1) < 24u) && ((unsigned)(xx + dx - 1) < 24u);
        if (valid) {
#pragma unroll
            for (int a = 0; a < 12; ++a) {
                i32x4 avr = *(const i32x4*)(lds + rb + aoff[a]);
                acc = __builtin_amdgcn_mfma_f32_32x32x16_bf16(
                    __builtin_bit_cast(bf16x8, avr),
                    __builtin_bit_cast(bf16x8, bcur[a]), acc, 0, 0, 0);
            }
        }
#pragma unroll
        for (int a = 0; a < 12; ++a) bcur[a] = bnxt[a];
    }
#undef STAGE2

    // epilogue: D col=(co,s); row=(r&3)+8*(r>>2)+4*half -> position in y-group
    const int co = lane & 15, s = (lane >> 4) & 1;
    const float bb = b2[co];
    const int plane676 = (w * 24 + xx) * 676;
#pragma unroll
    for (int r = 0; r < 16; ++r) {
        int rowD = (r & 3) + 8 * (r >> 2) + 4 * half;
        int pp = wid * 32 + rowD;
        int yo = pp / 12, ze = (pp - yo * 12) * 2;
        float v = fmaxf(acc[r] + bb, 0.f);
        y2b[(size_t)(plane676 + (y0 + yo + 1) * 26 + (ze + s + 1)) * 32 + co] = (ushort)f2bf(v);
    }
}

// ---------------- conv3: MFMA, branches in N cols 0/1 (proven) ----
#define RING3   20800
#define W3C_LDS 41600

__global__ __launch_bounds__(256) void conv3_mfma(
    const char* __restrict__ y2p, const char* __restrict__ Wp3c,
    const float* __restrict__ b3, float* __restrict__ outn) {
    __shared__ char lds[2 * RING3 + 5184];
    const int tid = threadIdx.x, lane = tid & 63, wid = tid >> 6;
    const int bid = blockIdx.x;
    const int wg = (bid & 7) * 216 + (bid >> 3);        // bijective (1728%8==0)
    const int w = wg / 72, r0 = wg % 72, xx = r0 / 3, y0 = (r0 % 3) * 8;

    const int col = lane & 15, g16 = (lane >> 4) & 3;
    const int pyA = (lane >> 3) & 1, pzA = lane & 7;
    int a3[9];
#pragma unroll
    for (int t = 0; t < 9; ++t) {
        int dy = t / 3, dz = t % 3;
        a3[t] = ((2 * wid + pyA + dy) * 26 + (pzA + dz)) * 80 + g16 * 16;
    }
    const bool bact = (col == 0 && g16 < 2) || (col == 1 && g16 >= 2);
    const int colsel = (col < 2) ? col : 0;
    const int b_base = W3C_LDS + colsel * 2592 + (g16 & 1) * 16;
    const int bmask = bact ? -1 : 0;

#pragma unroll
    for (int it = 0; it < 2; ++it) {
        int g = tid + it * 256;
        if (g < 324)
            __builtin_amdgcn_global_load_lds(
                (const __attribute__((address_space(1))) void*)(Wp3c + g * 16),
                (__attribute__((address_space(3))) void*)
                    (lds + W3C_LDS + ((tid & ~63) + it * 256) * 16),
                16, 0, 0);
    }

    f32x4 acc[3];
#pragma unroll
    for (int m = 0; m < 3; ++m) acc[m] = f32x4{0.f, 0.f, 0.f, 0.f};

#define STAGE3(ph_, rb_) do {                                                       \
    int dw_ = (ph_) / 3, dx_ = (ph_) % 3;                                           \
    int wc_ = min(max(w + dw_ - 1, 0), 23), xc_ = min(max(xx + dx_ - 1, 0), 23);    \
    const char* slab_ = y2p + (size_t)((wc_ * 24 + xc_) * 676 + y0 * 26) * 64;      \
    _Pragma("unroll")                                                               \
    for (int it_ = 0; it_ < 6; ++it_) {                                             \
        int g_ = tid + it_ * 256;                                                   \
        if (g_ < 1300) {                                                            \
            int c_ = g_ / 5, p_ = g_ - c_ * 5;                                      \
            if (p_ < 4)                                                             \
                __builtin_amdgcn_global_load_lds(                                   \
                    (const __attribute__((address_space(1))) void*)                 \
                        (slab_ + c_ * 64 + p_ * 16),                                \
                    (__attribute__((address_space(3))) void*)                       \
                        (lds + (rb_) + ((tid & ~63) + it_ * 256) * 16),             \
                    16, 0, 0);                                                      \
        }                                                                           \
    }                                                                               \
} while (0)

    STAGE3(0, 0);
    int ring = 0;
#pragma unroll 1
    for (int ph = 0; ph < 9; ++ph) {
        __syncthreads();
        if (ph < 8) STAGE3(ph + 1, ring ^ RING3);
        int dw = ph / 3, dx = ph % 3;
        bool valid = ((unsigned)(w + dw - 1) < 24u) && ((unsigned)(xx + dx - 1) < 24u);
        if (valid) {
#pragma unroll
            for (int tl = 0; tl < 9; ++tl) {
                int tap = ph * 9 + tl;
                i32x4 braw = *(const i32x4*)(lds + b_base + tap * 32);
                i32x4 bm;
                bm[0] = braw[0] & bmask; bm[1] = braw[1] & bmask;
                bm[2] = braw[2] & bmask; bm[3] = braw[3] & bmask;
#pragma unroll
                for (int m = 0; m < 3; ++m) {
                    i32x4 avr = *(const i32x4*)(lds + ring + a3[tl] + m * 640);
                    acc[m] = __builtin_amdgcn_mfma_f32_16x16x32_bf16(
                        __builtin_bit_cast(bf16x8, avr),
                        __builtin_bit_cast(bf16x8, bm), acc[m], 0, 0, 0);
                }
            }
        }
        ring ^= RING3;
    }
#undef STAGE3

    const float bv = b3[0];
    const int py = (lane >> 5) & 1, c4 = ((lane >> 4) & 1) * 4;
    const int yo = y0 + 2 * wid + py;
    float* obase = outn + ((size_t)(w * 24 + xx) * 24 + yo) * 24;
#pragma unroll
    for (int m = 0; m < 3; ++m) {
        float o[4];
#pragma unroll
        for (int r = 0; r < 4; ++r) {
            float mine = acc[m][r];
            float oth = __shfl_xor(mine, 1);
            o[r] = fmaxf(mine + bv, 0.f) + fmaxf(oth + bv, 0.f);
        }
        if (col == 0)
            *(float4*)(obase + m * 8 + c4) = make_float4(o[0], o[1], o[2], o[3]);
    }
}

extern "C" void kernel_launch(void* const* d_in, const int* in_sizes, int n_in,
                              void* d_out, int out_size, void* d_ws, size_t ws_size,
                              hipStream_t stream) {
    const float* x  = (const float*)d_in[0];
    const float* w1 = (const float*)d_in[1];
    const float* b1 = (const float*)d_in[2];
    const float* w2 = (const float*)d_in[3];
    const float* b2 = (const float*)d_in[4];
    const float* w3 = (const float*)d_in[5];
    const float* b3 = (const float*)d_in[6];
    float* out = (float*)d_out;
    char* ws = (char*)d_ws;
    if (ws_size < WS_NEED) return;

    float*  Wp1  = (float*)(ws + WP1_OFF);
    ushort* Wp3c = (ushort*)(ws + WP3C_OFF);
    ushort* Wp2T = (ushort*)(ws + WP2T_OFF);
    uint32_t* y1p_u32 = (uint32_t*)(ws + Y1P_OFF);
    const char* y1p_b = (const char*)(ws + Y1P_OFF);
    ushort* y2p = (ushort*)(ws + Y2P_OFF);

    prep_weights<<<444, 256, 0, stream>>>(w1, w2, w3, Wp1, Wp3c, Wp2T);
    zero_ws<<<2048, 256, 0, stream>>>((uint4*)(ws + Y1P_OFF),
                                      (int)((WS_NEED - Y1P_OFF) / 16));

    for (int n = 0; n < 8; ++n) {
        conv1_plane2<<<576, 576, 0, stream>>>(
            x + (size_t)n * S4, Wp1, b1, y1p_u32);
        conv2_mfma3<<<3456, 192, 0, stream>>>(
            y1p_b, (const char*)(ws + WP2T_OFF), b2, y2p);
        conv3_mfma<<<1728, 256, 0, stream>>>(
            (const char*)y2p, (const char*)(ws + WP3C_OFF), b3,
            out + (size_t)n * S4);
    }
}